// Round 7
// baseline (570.681 us; speedup 1.0000x reference)
//
#include <hip/hip_runtime.h>
#include <stdint.h>

// out[b,o,m] = sum_i in[b,i,m] * w[i,o,m]  (complex, fp32)
// B=32, Ci=Co=128, M=64*65=4160. One float2 per complex element.
//
// R7: wave-independent streaming -- NO LDS, NO barriers (R2-R6 all
// plateaued at ~3 TB/s effective under barrier-lockstep chunk staging;
// the 6.8 TB/s fill kernel is tiny independent waves).
// Wave job: 32b x 8o x 8modes. acc = 32 f2 (64 VGPR). Depth-2 register
// prefetch over k (12 x 8B loads/k); compiler emits counted vmcnt from
// issue order. W read-once from HBM; A (136MB) L1-shared by the 4 waves
// of a block (same mode-group) and L2-shared by the 4 blocks of a
// mode-group (XCD-chunked adjacency). 8320 wave-jobs -> self-balancing,
// tail ~= one short block.

typedef float f2 __attribute__((ext_vector_type(2)));

#define NB 32
#define CI 128
#define CO 128
#define MODES 4160
#define MW 8            // modes per wave
#define OW 8            // o per wave

// acc.lo += a.lo*w.lo - a.hi*w.hi ; acc.hi += a.lo*w.hi + a.hi*w.lo
#define CFMA(acc, av, wv)                                                      \
  asm("v_pk_fma_f32 %0, %1, %2, %0 op_sel:[0,0,0] op_sel_hi:[0,1,1]"           \
      : "+v"(acc) : "v"(av), "v"(wv));                                         \
  asm("v_pk_fma_f32 %0, %1, %2, %0 op_sel:[1,1,0] op_sel_hi:[1,0,1] "          \
      "neg_lo:[1,0,0]"                                                         \
      : "+v"(acc) : "v"(av), "v"(wv));

#define LOADK(aa, ww, apk, wpk)                                                \
  {                                                                            \
    _Pragma("unroll") for (int r = 0; r < 4; ++r) aa[r] = (apk)[r * AR];       \
    _Pragma("unroll") for (int q = 0; q < 8; ++q) ww[q] = (wpk)[q * WQ];       \
  }

#define COMP(aa, ww)                                                           \
  _Pragma("unroll") for (int r = 0; r < 4; ++r)                                \
  _Pragma("unroll") for (int q = 0; q < 8; ++q) { CFMA(acc[r][q], aa[r], ww[q]); }

__global__ __launch_bounds__(256, 3)
void cmul2d_kernel(const f2* __restrict__ Ig,
                   const f2* __restrict__ Wl,
                   f2* __restrict__ Og) {
    const int t   = threadIdx.x;
    const int bid = blockIdx.x;

    // XCD-chunked job map: 2080 = 8 XCDs x 260. The 4 o-blocks of one
    // mode-group are adjacent within an XCD -> A slice (256KB) L2-shared.
    const int jid = (bid & 7) * 260 + (bid >> 3);
    const int mg  = jid >> 2;           // 0..519 mode-group
    const int oq  = jid & 3;            // o-quarter (32 o)
    const int m0  = mg * MW;

    const int wave = t >> 6;            // 0..3
    const int o0   = __builtin_amdgcn_readfirstlane(oq * 32 + wave * OW);
    const int lane = t & 63;
    const int ml   = lane & 7;          // mode within group
    const int wkr  = lane >> 3;         // 0..7 -> 4 b-rows each

    const size_t AR = (size_t)CI * MODES;   // A b-row stride (f2)
    const size_t AK = MODES;                // A k stride
    const size_t WQ = MODES;                // W o stride
    const size_t WK = (size_t)CO * MODES;   // W k stride

    const f2* apk = Ig + (size_t)(wkr * 4) * AR + m0 + ml;   // A[b0][k=0][m]
    const f2* wpk = Wl + (size_t)o0 * MODES + m0 + ml;       // W[k=0][o0][m]

    f2 acc[4][8];
#pragma unroll
    for (int r = 0; r < 4; ++r)
#pragma unroll
        for (int q = 0; q < 8; ++q) acc[r][q] = (f2)(0.0f);

    f2 a0[4], w0[8], a1[4], w1[8];
    LOADK(a0, w0, apk, wpk);            // k = 0

#pragma unroll 1
    for (int k = 0; k < CI; k += 2) {
        apk += AK; wpk += WK;           // -> k+1
        LOADK(a1, w1, apk, wpk);        // issue k+1 (12 loads in flight)
        COMP(a0, w0);                   // compute k (waits its own 12)
        apk += AK; wpk += WK;           // -> k+2
        if (k + 2 < CI) LOADK(a0, w0, apk, wpk);
        COMP(a1, w1);                   // compute k+1
    }

    // stores: per (r,q) the 8 ml lanes are consecutive -> 64B segments
#pragma unroll
    for (int r = 0; r < 4; ++r) {
        const int b = wkr * 4 + r;
#pragma unroll
        for (int q = 0; q < 8; ++q) {
            Og[((size_t)b * CO + o0 + q) * MODES + m0 + ml] = acc[r][q];
        }
    }
}

extern "C" void kernel_launch(void* const* d_in, const int* in_sizes, int n_in,
                              void* d_out, int out_size, void* d_ws, size_t ws_size,
                              hipStream_t stream) {
    const f2* I = (const f2*)d_in[0];
    const f2* W = (const f2*)d_in[1];
    f2* O = (f2*)d_out;
    dim3 grid(2080);    // 520 mode-groups x 4 o-quarters
    dim3 block(256);    // 4 waves, each an independent 32b x 8o x 8m job
    cmul2d_kernel<<<grid, block, 0, stream>>>(I, W, O);
}

// Round 8
// 252.911 us; speedup vs baseline: 2.2564x; 2.2564x over previous
//
#include <hip/hip_runtime.h>
#include <stdint.h>

// out[b,o,m] = sum_i in[b,i,m] * w[i,o,m]  (complex, fp32)
// B=32, Ci=Co=128, M=64*65=4160. One float2 per complex element.
//
// R8 = R5 geometry (block 32b x 64o x 8modes, 512 thr, tile 4b x 8o,
// global_load_lds dwordx4, W o-row XOR swizzle, XCD-paired jobs) with ONLY
// the pipeline changed (A/B vs R5's 262us):
//   - 3 LDS buffers (72KB) instead of 2: issue-to-need = 2 chunk-periods
//   - DMA issue SPREAD: 1 gload_lds per kk-phase during compute (T3/T4),
//     not a 3-load burst between chunks
//   - VM_WAIT(3) steady state (never 0 until last chunk)
//   - s_setprio(1) around each FMA cluster (T5)

typedef float f2 __attribute__((ext_vector_type(2)));

#define NB 32
#define CI 128
#define CO 128
#define OT 64
#define MODES 4160
#define MPB 8
#define KC 4
#define NCHUNK (CI / KC)               // 32
#define ABUF_F2 (KC * NB * MPB)        // 1024 f2 =  8 KB
#define WBUF_F2 (KC * OT * MPB)        // 2048 f2 = 16 KB
#define BUF_F2  (ABUF_F2 + WBUF_F2)    // 24 KB per buffer

// acc.lo += a.lo*w.lo - a.hi*w.hi ; acc.hi += a.lo*w.hi + a.hi*w.lo
#define CFMA(acc, av, wv)                                                      \
  asm("v_pk_fma_f32 %0, %1, %2, %0 op_sel:[0,0,0] op_sel_hi:[0,1,1]"           \
      : "+v"(acc) : "v"(av), "v"(wv));                                         \
  asm("v_pk_fma_f32 %0, %1, %2, %0 op_sel:[1,1,0] op_sel_hi:[1,0,1] "          \
      "neg_lo:[1,0,0]"                                                         \
      : "+v"(acc) : "v"(av), "v"(wv));

#define VM_WAIT(N) asm volatile("s_waitcnt vmcnt(" #N ")" ::: "memory")

__device__ __forceinline__ void gload16(const f2* g, f2* l) {
    __builtin_amdgcn_global_load_lds(
        (const __attribute__((address_space(1))) uint32_t*)g,
        (__attribute__((address_space(3))) uint32_t*)l, 16, 0, 0);
}

// One of the 3 per-thread 16B DMA units of a K-chunk (identical to R5):
// WHICH=0: A, t <-> (kk=t>>7, b=(t>>2)&31, mlq=t&3), LDS f2 slot t*2.
// WHICH=1,2: W, j=(WHICH-1)*512+t <-> (kk=j>>8, op=(j>>2)&63, mlq=j&3),
//   logical o = op ^ ((op>>3)&1)  (involution), LDS f2 slot ABUF + j*2.
template <int WHICH>
__device__ __forceinline__ void stage_unit(const f2* __restrict__ Ig,
                                           const f2* __restrict__ Wl,
                                           f2* dst, int t, int m0,
                                           int obase, int k0) {
    if constexpr (WHICH == 0) {
        const int kk = t >> 7, b = (t >> 2) & 31, ml0 = (t & 3) << 1;
        gload16(Ig + (size_t)(b * CI + k0 + kk) * MODES + m0 + ml0,
                dst + t * 2);
    } else {
        constexpr int p = WHICH - 1;
        const int j  = p * 512 + WHICH * 0 + t + p * 0 + 512 * 0;  // j = p*512+t
        const int jj = p * 512 + t;
        const int kk = jj >> 8, op = (jj >> 2) & 63, ml0 = (jj & 3) << 1;
        const int o  = op ^ ((op >> 3) & 1);
        (void)j;
        gload16(Wl + (size_t)((k0 + kk) * CO + obase + o) * MODES + m0 + ml0,
                dst + ABUF_F2 + jj * 2);
    }
}

__global__ __launch_bounds__(512, 4)
void cmul2d_kernel(const f2* __restrict__ Ig,
                   const f2* __restrict__ Wl,
                   f2* __restrict__ Og) {
    __shared__ f2 lds[3 * BUF_F2];   // 72 KB -> 2 blocks/CU

    const int t = threadIdx.x;

    // XCD-chunked job map (1040 = 8 XCDs x 130); o-half pairs adjacent on
    // one XCD -> I's second read L2-hits.
    const int bid   = blockIdx.x;
    const int jid   = (bid & 7) * 130 + (bid >> 3);
    const int m0    = (jid >> 1) * MPB;
    const int obase = (jid & 1) * OT;

    const int ml = t & 7;      // mode lane
    const int s  = t >> 3;     // worker 0..63
    const int so = s & 7;      // o-group (8 o each)
    const int sb = s >> 3;     // b-group (4 b each) -- wave-uniform

    f2 acc[4][8];
#pragma unroll
    for (int r = 0; r < 4; ++r)
#pragma unroll
        for (int q = 0; q < 8; ++q) acc[r][q] = (f2)(0.0f);

    // prologue: fully stage chunks 0 and 1 (6 loads in flight / thread)
    stage_unit<0>(Ig, Wl, lds, t, m0, obase, 0);
    stage_unit<1>(Ig, Wl, lds, t, m0, obase, 0);
    stage_unit<2>(Ig, Wl, lds, t, m0, obase, 0);
    stage_unit<0>(Ig, Wl, lds + BUF_F2, t, m0, obase, KC);
    stage_unit<1>(Ig, Wl, lds + BUF_F2, t, m0, obase, KC);
    stage_unit<2>(Ig, Wl, lds + BUF_F2, t, m0, obase, KC);

#pragma unroll 1
    for (int c = 0; c < NCHUNK; ++c) {
        // queue: [chunk c's 3 (issued iter c-2), chunk c+1's 3 (iter c-1)]
        if (c < NCHUNK - 1) { VM_WAIT(3); } else { VM_WAIT(0); }
        __builtin_amdgcn_s_barrier();        // chunk c landed for all waves
        __builtin_amdgcn_sched_barrier(0);

        const f2* Ab = lds + (c % 3) * BUF_F2;
        const f2* Wb = Ab + ABUF_F2;
        f2* nbuf = lds + ((c + 2) % 3) * BUF_F2;   // read-done at iter c-1
        const bool more = (c + 2 < NCHUNK);
        const int  nk0  = (c + 2) * KC;

#pragma unroll
        for (int kk = 0; kk < KC; ++kk) {
            f2 a[4], w[8];
#pragma unroll
            for (int r = 0; r < 4; ++r)          // broadcast across workers
                a[r] = Ab[(kk * NB + sb * 4 + r) * MPB + ml];
#pragma unroll
            for (int q = 0; q < 8; ++q) {        // XOR-paired rows: 2-way, free
                const int o  = so * 8 + q;
                const int op = o ^ (so & 1);
                w[q] = Wb[(kk * OT + op) * MPB + ml];
            }
            // spread DMA issue: one 16B gload_lds per kk-phase (T3/T4)
            if (more) {
                if (kk == 0) stage_unit<0>(Ig, Wl, nbuf, t, m0, obase, nk0);
                else if (kk == 1) stage_unit<1>(Ig, Wl, nbuf, t, m0, obase, nk0);
                else if (kk == 2) stage_unit<2>(Ig, Wl, nbuf, t, m0, obase, nk0);
            }
            __builtin_amdgcn_sched_barrier(0);   // keep issue ahead of FMAs
            __builtin_amdgcn_s_setprio(1);       // T5: favor FMA cluster
#pragma unroll
            for (int r = 0; r < 4; ++r)
#pragma unroll
                for (int q = 0; q < 8; ++q) {
                    CFMA(acc[r][q], a[r], w[q]);
                }
            __builtin_amdgcn_s_setprio(0);
        }

        __builtin_amdgcn_sched_barrier(0);
        __builtin_amdgcn_s_barrier();        // all waves done reading buf c%3
    }

    // epilogue: per (b,o) the 8 ml lanes are consecutive -> 64B segments
#pragma unroll
    for (int r = 0; r < 4; ++r) {
        const int b = sb * 4 + r;
#pragma unroll
        for (int q = 0; q < 8; ++q) {
            const int o = obase + so * 8 + q;
            Og[(size_t)(b * CO + o) * MODES + m0 + ml] = acc[r][q];
        }
    }
}

extern "C" void kernel_launch(void* const* d_in, const int* in_sizes, int n_in,
                              void* d_out, int out_size, void* d_ws, size_t ws_size,
                              hipStream_t stream) {
    const f2* I = (const f2*)d_in[0];
    const f2* W = (const f2*)d_in[1];
    f2* O = (f2*)d_out;
    dim3 grid(1040);    // 520 mode-octets x 2 o-halves
    dim3 block(512);
    cmul2d_kernel<<<grid, block, 0, stream>>>(I, W, O);
}